// Round 1
// baseline (985.558 us; speedup 1.0000x reference)
//
#include <hip/hip_runtime.h>
#include <math.h>

// SSCA module, algebraically restructured:
//   Q      = queries @ Wq + bq                        [B, C, A]
//   FQ     = Wf @ Q   (per batch)                     [C, B*A]   (replaces F = feat@Wf)
//   bQ     = bf . Q                                   [B*A]
//   scores = feat @ FQ + bQ ; attn = softmax(scores/8)  -> d_out[0 .. 1M)
//   L      = sum_n attn                               [B*A]
//   T      = feat^T @ attn  (per batch)               [C, B*A]
//   out    = Wf1^T @ T + bf1 (x) L                    -> d_out[1M .. 3M)
// FLOPs: 27.9 GF vs 285.6 GF naive. All fp32 (vector FMA; no fp32 MFMA on CDNA4).

#define NB 16
#define HWD 1024      // H*W
#define CCH 2048      // C_IN == C_PROJ
#define DQD 512
#define NA 64
#define BAD 1024      // NB*NA

// ---------------- rowA GEMM: A row-major [M x K], B row-major [K x N] ----------------
// BM=128, BN=64, BK=16, 256 threads, 8x4 microtile.
// MODE 0: qproj  (M=32768 rows=(b,f), K=512, N=64; out scatter Qcat[f*BA + b*64 + a] + bq)
// MODE 1: FQ     (M=2048(c), K=2048(f), N=1024(ba); out FQcat row-major)
template <int MODE>
__global__ __launch_bounds__(256) void k_gemm_rowA(
    const float* __restrict__ Am, const float* __restrict__ Bm,
    const float* __restrict__ bias, float* __restrict__ Co,
    int K, int lda, int ldb)
{
    __shared__ float As[16][132];   // [kk][m], pad->528B row stride (16B aligned, <=2-way bank)
    __shared__ float Bs[16][68];    // [kk][n], 272B row stride (16B aligned)
    const int tid = threadIdx.x;
    const int tx = tid & 15, ty = tid >> 4;
    const int n0 = blockIdx.x * 64;
    const int m0 = blockIdx.y * 128;
    const int v1 = tid + 256;

    float acc[8][4];
#pragma unroll
    for (int i = 0; i < 8; ++i)
#pragma unroll
        for (int j = 0; j < 4; ++j) acc[i][j] = 0.f;

    for (int k0 = 0; k0 < K; k0 += 16) {
        // A tile 128x16 -> transpose into As[kk][m]. 512 float4, 2/thread.
        float4 a0 = *(const float4*)&Am[(size_t)(m0 + (tid >> 2)) * lda + k0 + (tid & 3) * 4];
        float4 a1 = *(const float4*)&Am[(size_t)(m0 + (v1 >> 2)) * lda + k0 + (v1 & 3) * 4];
        // B tile 16x64. 256 float4, 1/thread.
        float4 bv = *(const float4*)&Bm[(size_t)(k0 + (tid >> 4)) * ldb + n0 + (tid & 15) * 4];
        __syncthreads();
        {
            int r = tid >> 2, c4 = tid & 3;
            As[c4 * 4 + 0][r] = a0.x; As[c4 * 4 + 1][r] = a0.y;
            As[c4 * 4 + 2][r] = a0.z; As[c4 * 4 + 3][r] = a0.w;
            r = v1 >> 2; c4 = v1 & 3;
            As[c4 * 4 + 0][r] = a1.x; As[c4 * 4 + 1][r] = a1.y;
            As[c4 * 4 + 2][r] = a1.z; As[c4 * 4 + 3][r] = a1.w;
            *(float4*)&Bs[tid >> 4][(tid & 15) * 4] = bv;
        }
        __syncthreads();
#pragma unroll
        for (int kk = 0; kk < 16; ++kk) {
            float4 x0 = *(const float4*)&As[kk][ty * 8];
            float4 x1 = *(const float4*)&As[kk][ty * 8 + 4];
            float4 y  = *(const float4*)&Bs[kk][tx * 4];
            float ar[8] = {x0.x, x0.y, x0.z, x0.w, x1.x, x1.y, x1.z, x1.w};
            float br[4] = {y.x, y.y, y.z, y.w};
#pragma unroll
            for (int i = 0; i < 8; ++i)
#pragma unroll
                for (int j = 0; j < 4; ++j)
                    acc[i][j] = fmaf(ar[i], br[j], acc[i][j]);
        }
    }

    if (MODE == 0) {
        // rows are (b,f): b = row>>11, f = row&2047; write Qcat[f*BA + b*64 + a] (+bq[a])
        float4 bqv = *(const float4*)&bias[n0 + tx * 4];
        float bqa[4] = {bqv.x, bqv.y, bqv.z, bqv.w};
#pragma unroll
        for (int i = 0; i < 8; ++i) {
            int row = m0 + ty * 8 + i;
            int b = row >> 11, f = row & 2047;
            float4 o;
            o.x = acc[i][0] + bqa[0]; o.y = acc[i][1] + bqa[1];
            o.z = acc[i][2] + bqa[2]; o.w = acc[i][3] + bqa[3];
            *(float4*)&Co[(size_t)f * BAD + b * 64 + tx * 4] = o;
        }
    } else {
#pragma unroll
        for (int i = 0; i < 8; ++i) {
            int row = m0 + ty * 8 + i;
            float4 o;
            o.x = acc[i][0]; o.y = acc[i][1]; o.z = acc[i][2]; o.w = acc[i][3];
            *(float4*)&Co[(size_t)row * BAD + n0 + tx * 4] = o;
        }
    }
}

// ---------------- bQ[ba] = sum_f bf[f] * Qcat[f*BA + ba] ----------------
__global__ __launch_bounds__(64) void k_bq(const float* __restrict__ Qcat,
                                           const float* __restrict__ bf,
                                           float* __restrict__ bQ)
{
    int ba = blockIdx.x * 64 + threadIdx.x;   // grid 16, block 64
    float s = 0.f;
#pragma unroll 8
    for (int f = 0; f < CCH; ++f) s = fmaf(bf[f], Qcat[(size_t)f * BAD + ba], s);
    bQ[ba] = s;
}

// ---------------- scores + softmax ----------------
// Per block: one batch b, 64 n-rows, all 64 attrs. BM=64, BN=64, BK=16, 4x4 microtile.
__global__ __launch_bounds__(256) void k_scores(
    const float* __restrict__ feat, const float* __restrict__ FQ,
    const float* __restrict__ bQ, float* __restrict__ attn_out)
{
    __shared__ float As[16][68];   // [kk(c)][n]
    __shared__ float Bs[16][68];   // [kk(c)][a]
    const int tid = threadIdx.x;
    const int tx = tid & 15, ty = tid >> 4;
    const int b = blockIdx.y;
    const int n0 = blockIdx.x * 64;
    const float* fbase = feat + ((size_t)b * HWD + n0) * CCH;
    const float* fqb = FQ + b * 64;

    float acc[4][4];
#pragma unroll
    for (int i = 0; i < 4; ++i)
#pragma unroll
        for (int j = 0; j < 4; ++j) acc[i][j] = 0.f;

    for (int k0 = 0; k0 < CCH; k0 += 16) {
        // A tile 64(n) x 16(c): 256 float4, 1/thread; transpose into As[kk][n]
        float4 av = *(const float4*)&fbase[(size_t)(tid >> 2) * CCH + k0 + (tid & 3) * 4];
        // B tile 16(c) x 64(a): FQ rows stride BA
        float4 bv = *(const float4*)&fqb[(size_t)(k0 + (tid >> 4)) * BAD + (tid & 15) * 4];
        __syncthreads();
        {
            int r = tid >> 2, c4 = tid & 3;
            As[c4 * 4 + 0][r] = av.x; As[c4 * 4 + 1][r] = av.y;
            As[c4 * 4 + 2][r] = av.z; As[c4 * 4 + 3][r] = av.w;
            *(float4*)&Bs[tid >> 4][(tid & 15) * 4] = bv;
        }
        __syncthreads();
#pragma unroll
        for (int kk = 0; kk < 16; ++kk) {
            float4 x0 = *(const float4*)&As[kk][ty * 4];
            float4 y  = *(const float4*)&Bs[kk][tx * 4];
            float ar[4] = {x0.x, x0.y, x0.z, x0.w};
            float br[4] = {y.x, y.y, y.z, y.w};
#pragma unroll
            for (int i = 0; i < 4; ++i)
#pragma unroll
                for (int j = 0; j < 4; ++j)
                    acc[i][j] = fmaf(ar[i], br[j], acc[i][j]);
        }
    }

    // softmax over a (64 wide): each row owned by 16 lanes (tx), same wave.
    float4 bqv = *(const float4*)&bQ[b * 64 + tx * 4];
    float bqa[4] = {bqv.x, bqv.y, bqv.z, bqv.w};
#pragma unroll
    for (int i = 0; i < 4; ++i) {
        float l[4];
#pragma unroll
        for (int j = 0; j < 4; ++j) l[j] = (acc[i][j] + bqa[j]) * 0.125f;
        float m = fmaxf(fmaxf(l[0], l[1]), fmaxf(l[2], l[3]));
        m = fmaxf(m, __shfl_xor(m, 1));
        m = fmaxf(m, __shfl_xor(m, 2));
        m = fmaxf(m, __shfl_xor(m, 4));
        m = fmaxf(m, __shfl_xor(m, 8));
        float e[4], s = 0.f;
#pragma unroll
        for (int j = 0; j < 4; ++j) { e[j] = expf(l[j] - m); s += e[j]; }
        s += __shfl_xor(s, 1);
        s += __shfl_xor(s, 2);
        s += __shfl_xor(s, 4);
        s += __shfl_xor(s, 8);
        float inv = 1.f / s;
        float4 o;
        o.x = e[0] * inv; o.y = e[1] * inv; o.z = e[2] * inv; o.w = e[3] * inv;
        *(float4*)&attn_out[((size_t)b * HWD + n0 + ty * 4 + i) * NA + tx * 4] = o;
    }
}

// ---------------- L[b*64+a] = sum_n attn[b,n,a] ----------------
__global__ __launch_bounds__(256) void k_lsum(const float* __restrict__ attn,
                                              float* __restrict__ L)
{
    int b = blockIdx.x;
    int a = threadIdx.x & 63, g = threadIdx.x >> 6;
    float s = 0.f;
#pragma unroll 8
    for (int n = g * 256; n < (g + 1) * 256; ++n)
        s += attn[((size_t)b * HWD + n) * NA + a];
    __shared__ float p[4][64];
    p[g][a] = s;
    __syncthreads();
    if (g == 0) L[b * 64 + a] = p[0][a] + p[1][a] + p[2][a] + p[3][a];
}

// ---------------- colA GEMM: A stored K-major (contiguous along M) ----------------
// BM=128, BN=64, BK=16, 256 threads, 8x4 microtile. No transpose needed on A stage.
// MODE 0: T = feat^T @ attn, per batch (grid.y = b). K=1024(n), lda=2048, ldb=64.
//         out Tcat[m*BA + b*64 + a]
// MODE 1: out = Wf1^T @ Tcat + bf1 (x) L (grid.y = ntile). K=2048, lda=2048, ldb=1024.
//         out d_out[nt*131072 + c*64 + a]
template <int MODE>
__global__ __launch_bounds__(256) void k_gemm_colA(
    const float* __restrict__ Am, const float* __restrict__ Bm,
    const float* __restrict__ bias, const float* __restrict__ Lv,
    float* __restrict__ Co, int K, int lda, int ldb)
{
    __shared__ float As[16][132];
    __shared__ float Bs[16][68];
    const int tid = threadIdx.x;
    const int tx = tid & 15, ty = tid >> 4;
    const int m0 = blockIdx.x * 128;
    const int v1 = tid + 256;

    const float* Ab;
    const float* Bb;
    int n0;
    if (MODE == 0) {
        Ab = Am + (size_t)blockIdx.y * HWD * CCH;
        Bb = Bm + (size_t)blockIdx.y * HWD * NA;
        n0 = 0;
    } else {
        Ab = Am; Bb = Bm;
        n0 = blockIdx.y * 64;
    }

    float acc[8][4];
#pragma unroll
    for (int i = 0; i < 8; ++i)
#pragma unroll
        for (int j = 0; j < 4; ++j) acc[i][j] = 0.f;

    for (int k0 = 0; k0 < K; k0 += 16) {
        // A tile: 16(kk) x 128(m), contiguous along m -> direct stage, coalesced.
        float4 a0 = *(const float4*)&Ab[(size_t)(k0 + (tid >> 5)) * lda + m0 + (tid & 31) * 4];
        float4 a1 = *(const float4*)&Ab[(size_t)(k0 + (v1 >> 5)) * lda + m0 + (v1 & 31) * 4];
        float4 bv = *(const float4*)&Bb[(size_t)(k0 + (tid >> 4)) * ldb + n0 + (tid & 15) * 4];
        __syncthreads();
        *(float4*)&As[tid >> 5][(tid & 31) * 4] = a0;
        *(float4*)&As[v1 >> 5][(v1 & 31) * 4] = a1;
        *(float4*)&Bs[tid >> 4][(tid & 15) * 4] = bv;
        __syncthreads();
#pragma unroll
        for (int kk = 0; kk < 16; ++kk) {
            float4 x0 = *(const float4*)&As[kk][ty * 8];
            float4 x1 = *(const float4*)&As[kk][ty * 8 + 4];
            float4 y  = *(const float4*)&Bs[kk][tx * 4];
            float ar[8] = {x0.x, x0.y, x0.z, x0.w, x1.x, x1.y, x1.z, x1.w};
            float br[4] = {y.x, y.y, y.z, y.w};
#pragma unroll
            for (int i = 0; i < 8; ++i)
#pragma unroll
                for (int j = 0; j < 4; ++j)
                    acc[i][j] = fmaf(ar[i], br[j], acc[i][j]);
        }
    }

    if (MODE == 0) {
        int b = blockIdx.y;
#pragma unroll
        for (int i = 0; i < 8; ++i) {
            float4 o;
            o.x = acc[i][0]; o.y = acc[i][1]; o.z = acc[i][2]; o.w = acc[i][3];
            *(float4*)&Co[(size_t)(m0 + ty * 8 + i) * BAD + b * 64 + tx * 4] = o;
        }
    } else {
        int nt = blockIdx.y;
        float4 lv4 = *(const float4*)&Lv[nt * 64 + tx * 4];
        float la[4] = {lv4.x, lv4.y, lv4.z, lv4.w};
#pragma unroll
        for (int i = 0; i < 8; ++i) {
            int c = m0 + ty * 8 + i;
            float bc = bias[c];
            float4 o;
            o.x = fmaf(bc, la[0], acc[i][0]); o.y = fmaf(bc, la[1], acc[i][1]);
            o.z = fmaf(bc, la[2], acc[i][2]); o.w = fmaf(bc, la[3], acc[i][3]);
            *(float4*)&Co[(size_t)nt * (CCH * NA) + (size_t)c * NA + tx * 4] = o;
        }
    }
}

extern "C" void kernel_launch(void* const* d_in, const int* in_sizes, int n_in,
                              void* d_out, int out_size, void* d_ws, size_t ws_size,
                              hipStream_t stream)
{
    (void)in_sizes; (void)n_in; (void)out_size; (void)ws_size;
    const float* queries  = (const float*)d_in[0];
    const float* features = (const float*)d_in[1];
    const float* Wq  = (const float*)d_in[2];
    const float* bq  = (const float*)d_in[3];
    const float* Wf  = (const float*)d_in[4];
    const float* bf  = (const float*)d_in[5];
    const float* Wf1 = (const float*)d_in[6];
    const float* bf1 = (const float*)d_in[7];
    float* out = (float*)d_out;
    float* ws  = (float*)d_ws;

    // ws layout (floats): buf0 [C x BA] reused (Qcat then Tcat), buf1 [C x BA] (FQcat),
    // bQ [BA], L [BA]. Total ~16.8 MB.
    float* Qcat  = ws;                 // later reused as Tcat (last read in k_gemm_rowA<1>/k_bq)
    float* FQcat = ws + 2097152;
    float* Tcat  = ws;                 // alias of Qcat region, safe: stream-serialized
    float* bQ    = ws + 4194304;
    float* L     = ws + 4194304 + 1024;

    // 1. Q projection: Qcat[f*BA + b*64 + a] = queries[b,f,:] @ Wq + bq
    k_gemm_rowA<0><<<dim3(1, 256), 256, 0, stream>>>(queries, Wq, bq, Qcat, DQD, DQD, NA);
    // 2. bQ = bf . Q
    k_bq<<<dim3(16), 64, 0, stream>>>(Qcat, bf, bQ);
    // 3. FQcat = Wf @ Qcat   [2048 x 1024]
    k_gemm_rowA<1><<<dim3(16, 16), 256, 0, stream>>>(Wf, Qcat, nullptr, FQcat, CCH, CCH, BAD);
    // 4. attn = softmax((feat @ FQcat + bQ)/8)  -> d_out[0 .. 1048576)
    k_scores<<<dim3(16, 16), 256, 0, stream>>>(features, FQcat, bQ, out);
    // 5. L = sum_n attn
    k_lsum<<<dim3(16), 256, 0, stream>>>(out, L);
    // 6. Tcat = feat^T @ attn (per batch)   [2048 x 1024]  (overwrites Qcat region)
    k_gemm_colA<0><<<dim3(16, 16), 256, 0, stream>>>(features, out, nullptr, nullptr,
                                                     Tcat, HWD, CCH, NA);
    // 7. out = Wf1^T @ Tcat + bf1 (x) L  -> d_out[1048576 ..)
    k_gemm_colA<1><<<dim3(16, 16), 256, 0, stream>>>(Wf1, Tcat, bf1, L,
                                                     out + 1048576, CCH, CCH, BAD);
}

// Round 3
// 489.052 us; speedup vs baseline: 2.0152x; 2.0152x over previous
//
#include <hip/hip_runtime.h>
#include <math.h>

// SSCA restructured, all big contractions on MFMA via split-bf16 (hi+lo, 3-MFMA):
//   Q    = queries @ Wq + bq              -> QT hi/lo [ba][cp]      (MFMA)
//   bQ   = bf . Q                         -> [ba]
//   FQ   = Wf @ Q                         -> FQT hi/lo [ba][ci]     (MFMA)
//   attn = softmax((feat @ FQ + bQ)/8)    -> d_out fp32 + attnT hi/lo [ba][n] (MFMA)
//   L    = sum_n attn                     -> [ba]
//   T    = feat^T @ attn (per b)          -> TT hi/lo [ba][ci]      (MFMA, LDS-transpose A)
//   out  = Wf1^T @ T + bf1 (x) L          -> d_out fp32 [b][c][a]   (MFMA, LDS-transpose A)
// FLOPs 27.9 GF dense (x3 split on MFMA pipe). ws usage ~16.4 MB (round-1-proven bound).

#define CCH 2048
#define HWD 1024
#define BAD 1024
#define DQD 512
#define NA  64

typedef __attribute__((ext_vector_type(8))) short bf16x8;
typedef __attribute__((ext_vector_type(4))) float f32x4;
typedef __attribute__((ext_vector_type(4))) unsigned short us4;
typedef __attribute__((ext_vector_type(8))) unsigned short us8;

// truncation split: hi = trunc-bf16(v); lo = trunc-bf16(v - hi). lo's rounding
// dominates -> ~2^-16 rel precision, 4 VALU/elem.
__device__ __forceinline__ unsigned short bfhi(float v) {
    return (unsigned short)(__float_as_uint(v) >> 16);
}
__device__ __forceinline__ float bfres(float v) {
    return v - __uint_as_float(__float_as_uint(v) & 0xffff0000u);
}
__device__ __forceinline__ float bf2f(unsigned short h) {
    return __uint_as_float(((unsigned)h) << 16);
}

// ---------- tiny: WqT hi/lo [a][dq] from Wq [dq][a] ----------
__global__ __launch_bounds__(256) void k_convWq(const float* __restrict__ Wq,
    unsigned short* __restrict__ hi, unsigned short* __restrict__ lo)
{
    __shared__ float t[64][65];
    const int tid = threadIdx.x;
    const int k0 = blockIdx.x * 64;
#pragma unroll
    for (int r = 0; r < 4; ++r) {
        int kr = (tid >> 4) + r * 16;
        int cc = (tid & 15) * 4;
        float4 v = *(const float4*)&Wq[(size_t)(k0 + kr) * NA + cc];
        t[kr][cc] = v.x; t[kr][cc + 1] = v.y; t[kr][cc + 2] = v.z; t[kr][cc + 3] = v.w;
    }
    __syncthreads();
#pragma unroll
    for (int r = 0; r < 2; ++r) {
        int a = (tid >> 3) + r * 32;
        int g = tid & 7;
        us8 h8, l8;
#pragma unroll
        for (int j = 0; j < 8; ++j) {
            float v = t[g * 8 + j][a];
            h8[j] = bfhi(v); l8[j] = bfhi(bfres(v));
        }
        *(us8*)&hi[(size_t)a * DQD + k0 + g * 8] = h8;
        *(us8*)&lo[(size_t)a * DQD + k0 + g * 8] = l8;
    }
}

// ---------- GEMM, A fp32 [M][K] k-contiguous (convert in staging), B bf16 hi/lo [N][K] ----------
// 64x64 tile, 256 thr (4 waves), 16x16x32 MFMA, split-3.
// EPI 0 (FQ):    Oh/Ol[(gy*64 + nloc)*CCH + m]          (bf16 hi/lo, transposed)
// EPI 1 (qproj): Oh/Ol[((m>>11)*64 + nloc)*CCH + (m&2047)], value += bias[nloc]
template <int EPI>
__global__ __launch_bounds__(256) void k_gemm_A32(
    const float* __restrict__ A,
    const unsigned short* __restrict__ Bh, const unsigned short* __restrict__ Bl,
    const float* __restrict__ bias,
    unsigned short* __restrict__ Oh, unsigned short* __restrict__ Ol,
    int K, int ldb)
{
    __shared__ unsigned short AsH[4][64][8], AsL[4][64][8], BsH[4][64][8], BsL[4][64][8];
    const int tid = threadIdx.x;
    const int m0 = blockIdx.x * 64, gy = blockIdx.y;
    const int w = tid >> 6, l = tid & 63, lr = l & 15, lg = l >> 4;
    const int sm = tid >> 2, sk = tid & 3, kq = sk * 4;

    const float* pA = A + (size_t)(m0 + sm) * K;
    const unsigned short* pBh = Bh + (size_t)(gy * 64 + sm) * ldb + sk * 8;
    const unsigned short* pBl = Bl + (size_t)(gy * 64 + sm) * ldb + sk * 8;

    f32x4 acc[4] = {{0.f,0.f,0.f,0.f},{0.f,0.f,0.f,0.f},{0.f,0.f,0.f,0.f},{0.f,0.f,0.f,0.f}};

    for (int k0 = 0; k0 < K; k0 += 32) {
        float4 a0 = *(const float4*)&pA[k0 + kq];
        float4 a1 = *(const float4*)&pA[k0 + 16 + kq];
        uint4 vbh = *(const uint4*)pBh; uint4 vbl = *(const uint4*)pBl;
        pBh += 32; pBl += 32;
        us4 h0, l0, h1, l1;
        float a0r[4] = {a0.x, a0.y, a0.z, a0.w}, a1r[4] = {a1.x, a1.y, a1.z, a1.w};
#pragma unroll
        for (int j = 0; j < 4; ++j) {
            h0[j] = bfhi(a0r[j]); l0[j] = bfhi(bfres(a0r[j]));
            h1[j] = bfhi(a1r[j]); l1[j] = bfhi(bfres(a1r[j]));
        }
        __syncthreads();
        *(us4*)&AsH[kq >> 3][sm][kq & 7] = h0;
        *(us4*)&AsL[kq >> 3][sm][kq & 7] = l0;
        *(us4*)&AsH[2 + (kq >> 3)][sm][kq & 7] = h1;
        *(us4*)&AsL[2 + (kq >> 3)][sm][kq & 7] = l1;
        *(uint4*)&BsH[sk][sm][0] = vbh;
        *(uint4*)&BsL[sk][sm][0] = vbl;
        __syncthreads();
        bf16x8 afh = *(const bf16x8*)&AsH[lg][w * 16 + lr][0];
        bf16x8 afl = *(const bf16x8*)&AsL[lg][w * 16 + lr][0];
#pragma unroll
        for (int nt = 0; nt < 4; ++nt) {
            bf16x8 bfh = *(const bf16x8*)&BsH[lg][nt * 16 + lr][0];
            bf16x8 bfl = *(const bf16x8*)&BsL[lg][nt * 16 + lr][0];
            acc[nt] = __builtin_amdgcn_mfma_f32_16x16x32_bf16(afh, bfh, acc[nt], 0, 0, 0);
            acc[nt] = __builtin_amdgcn_mfma_f32_16x16x32_bf16(afh, bfl, acc[nt], 0, 0, 0);
            acc[nt] = __builtin_amdgcn_mfma_f32_16x16x32_bf16(afl, bfh, acc[nt], 0, 0, 0);
        }
    }

    const int mrow0 = m0 + w * 16 + lg * 4;
    if (EPI == 0) {
#pragma unroll
        for (int nt = 0; nt < 4; ++nt) {
            int nn = gy * 64 + nt * 16 + lr;
            us4 h, lo;
#pragma unroll
            for (int j = 0; j < 4; ++j) {
                float v = acc[nt][j];
                h[j] = bfhi(v); lo[j] = bfhi(bfres(v));
            }
            *(us4*)&Oh[(size_t)nn * CCH + mrow0] = h;
            *(us4*)&Ol[(size_t)nn * CCH + mrow0] = lo;
        }
    } else {
        const int b = mrow0 >> 11, cp = mrow0 & 2047;
#pragma unroll
        for (int nt = 0; nt < 4; ++nt) {
            int nloc = nt * 16 + lr;
            float bb = bias[nloc];
            int row = b * 64 + nloc;
            us4 h, lo;
#pragma unroll
            for (int j = 0; j < 4; ++j) {
                float v = acc[nt][j] + bb;
                h[j] = bfhi(v); lo[j] = bfhi(bfres(v));
            }
            *(us4*)&Oh[(size_t)row * CCH + cp] = h;
            *(us4*)&Ol[(size_t)row * CCH + cp] = lo;
        }
    }
}

// ---------- bQ[ba] = sum_cp bf[cp] * Q[cp][ba] (from QT hi/lo) ----------
__global__ __launch_bounds__(256) void k_bq(const unsigned short* __restrict__ QTh,
    const unsigned short* __restrict__ QTl, const float* __restrict__ bf,
    float* __restrict__ bQ)
{
    const int row = blockIdx.x, tid = threadIdx.x;
    us8 h = *(const us8*)(QTh + (size_t)row * CCH + tid * 8);
    us8 l = *(const us8*)(QTl + (size_t)row * CCH + tid * 8);
    float s = 0.f;
#pragma unroll
    for (int j = 0; j < 8; ++j)
        s = fmaf(bf2f(h[j]) + bf2f(l[j]), bf[tid * 8 + j], s);
#pragma unroll
    for (int off = 1; off < 64; off <<= 1) s += __shfl_xor(s, off);
    __shared__ float ps[4];
    if ((tid & 63) == 0) ps[tid >> 6] = s;
    __syncthreads();
    if (tid == 0) bQ[row] = ps[0] + ps[1] + ps[2] + ps[3];
}

// ---------- scores + softmax; emits attn fp32 AND attnT hi/lo [ba][n] ----------
__global__ __launch_bounds__(256) void k_scores(
    const float* __restrict__ feat,
    const unsigned short* __restrict__ FQh, const unsigned short* __restrict__ FQl,
    const float* __restrict__ bQ, float* __restrict__ attn,
    unsigned short* __restrict__ ATh, unsigned short* __restrict__ ATl)
{
    __shared__ unsigned short AsH[4][64][8], AsL[4][64][8], BsH[4][64][8], BsL[4][64][8];
    const int tid = threadIdx.x;
    const int b = blockIdx.y, n0 = blockIdx.x * 64;
    const int w = tid >> 6, l = tid & 63, lr = l & 15, lg = l >> 4;
    const int sm = tid >> 2, sk = tid & 3, kq = sk * 4;

    const float* fb = feat + ((size_t)b * HWD + n0) * CCH;
    const unsigned short* pBh = FQh + (size_t)(b * 64 + sm) * CCH + sk * 8;
    const unsigned short* pBl = FQl + (size_t)(b * 64 + sm) * CCH + sk * 8;

    f32x4 acc[4] = {{0.f,0.f,0.f,0.f},{0.f,0.f,0.f,0.f},{0.f,0.f,0.f,0.f},{0.f,0.f,0.f,0.f}};

    for (int k0 = 0; k0 < CCH; k0 += 32) {
        float4 a0 = *(const float4*)&fb[(size_t)sm * CCH + k0 + kq];
        float4 a1 = *(const float4*)&fb[(size_t)sm * CCH + k0 + 16 + kq];
        uint4 vbh = *(const uint4*)pBh; uint4 vbl = *(const uint4*)pBl;
        pBh += 32; pBl += 32;
        us4 h0, l0, h1, l1;
        float a0r[4] = {a0.x, a0.y, a0.z, a0.w}, a1r[4] = {a1.x, a1.y, a1.z, a1.w};
#pragma unroll
        for (int j = 0; j < 4; ++j) {
            h0[j] = bfhi(a0r[j]); l0[j] = bfhi(bfres(a0r[j]));
            h1[j] = bfhi(a1r[j]); l1[j] = bfhi(bfres(a1r[j]));
        }
        __syncthreads();
        *(us4*)&AsH[kq >> 3][sm][kq & 7] = h0;
        *(us4*)&AsL[kq >> 3][sm][kq & 7] = l0;
        *(us4*)&AsH[2 + (kq >> 3)][sm][kq & 7] = h1;
        *(us4*)&AsL[2 + (kq >> 3)][sm][kq & 7] = l1;
        *(uint4*)&BsH[sk][sm][0] = vbh;
        *(uint4*)&BsL[sk][sm][0] = vbl;
        __syncthreads();
        bf16x8 afh = *(const bf16x8*)&AsH[lg][w * 16 + lr][0];
        bf16x8 afl = *(const bf16x8*)&AsL[lg][w * 16 + lr][0];
#pragma unroll
        for (int nt = 0; nt < 4; ++nt) {
            bf16x8 bfh = *(const bf16x8*)&BsH[lg][nt * 16 + lr][0];
            bf16x8 bfl = *(const bf16x8*)&BsL[lg][nt * 16 + lr][0];
            acc[nt] = __builtin_amdgcn_mfma_f32_16x16x32_bf16(afh, bfh, acc[nt], 0, 0, 0);
            acc[nt] = __builtin_amdgcn_mfma_f32_16x16x32_bf16(afh, bfl, acc[nt], 0, 0, 0);
            acc[nt] = __builtin_amdgcn_mfma_f32_16x16x32_bf16(afl, bfh, acc[nt], 0, 0, 0);
        }
    }

    // softmax over 64 attrs; row n = n0 + w*16 + lg*4 + j, col a = nt*16 + lr.
    float bq4[4];
#pragma unroll
    for (int nt = 0; nt < 4; ++nt) bq4[nt] = bQ[b * NA + nt * 16 + lr];
#pragma unroll
    for (int j = 0; j < 4; ++j) {
        float v[4];
#pragma unroll
        for (int nt = 0; nt < 4; ++nt) v[nt] = (acc[nt][j] + bq4[nt]) * 0.125f;
        float m = fmaxf(fmaxf(v[0], v[1]), fmaxf(v[2], v[3]));
        m = fmaxf(m, __shfl_xor(m, 1));
        m = fmaxf(m, __shfl_xor(m, 2));
        m = fmaxf(m, __shfl_xor(m, 4));
        m = fmaxf(m, __shfl_xor(m, 8));
        float e[4], s = 0.f;
#pragma unroll
        for (int nt = 0; nt < 4; ++nt) { e[nt] = expf(v[nt] - m); s += e[nt]; }
        s += __shfl_xor(s, 1);
        s += __shfl_xor(s, 2);
        s += __shfl_xor(s, 4);
        s += __shfl_xor(s, 8);
        float inv = 1.f / s;
        const int nr = n0 + w * 16 + lg * 4 + j;
#pragma unroll
        for (int nt = 0; nt < 4; ++nt) {
            float av = e[nt] * inv;
            attn[((size_t)b * HWD + nr) * NA + nt * 16 + lr] = av;
            size_t trow = (size_t)(b * 64 + nt * 16 + lr) * HWD + nr;
            ATh[trow] = bfhi(av);
            ATl[trow] = bfhi(bfres(av));
        }
    }
}

// ---------- L partials + final ----------
__global__ __launch_bounds__(256) void k_lsum1(const float* __restrict__ attn,
                                               float* __restrict__ part)
{
    const int g = blockIdx.x, b = blockIdx.y;
    const int a = threadIdx.x & 63, q = threadIdx.x >> 6;
    float s = 0.f;
#pragma unroll 4
    for (int n = g * 64 + q * 16; n < g * 64 + q * 16 + 16; ++n)
        s += attn[((size_t)b * HWD + n) * NA + a];
    __shared__ float p[4][64];
    p[q][a] = s;
    __syncthreads();
    if (q == 0) part[(size_t)g * BAD + b * NA + a] = p[0][a] + p[1][a] + p[2][a] + p[3][a];
}

__global__ __launch_bounds__(64) void k_lsum2(const float* __restrict__ part,
                                              float* __restrict__ L)
{
    int ba = blockIdx.x * 64 + threadIdx.x;
    float s = 0.f;
#pragma unroll
    for (int g = 0; g < 16; ++g) s += part[(size_t)g * BAD + ba];
    L[ba] = s;
}

// ---------- GEMM, A from k-major fp32 G[k][m] via XOR-swizzled LDS transpose ----------
// D[m][n'] = sum_k G[k][m] * Bt[n'][k].  64x64 tile, split-3 MFMA.
// EPI 0 (tmat): Oh/Ol[(gy*64 + nloc)*CCH + m]  bf16 hi/lo
// EPI 1 (out) : Ofp[(nn>>6)*CCH*NA + m*NA + (nn&63)] = acc + bias[m]*Lv[nn]
template <int EPI>
__global__ __launch_bounds__(256) void k_gemm_T(
    const float* __restrict__ G,
    const unsigned short* __restrict__ Bh, const unsigned short* __restrict__ Bl,
    unsigned short* __restrict__ Oh, unsigned short* __restrict__ Ol,
    float* __restrict__ Ofp, const float* __restrict__ bias, const float* __restrict__ Lv,
    int K, int ldg, int ldb, long gslab)
{
    __shared__ float At[2048];                         // [32 k][64 m] XOR-swizzled
    __shared__ unsigned short BsH[4][64][8], BsL[4][64][8];
    const int tid = threadIdx.x;
    const int m0 = blockIdx.x * 64, gy = blockIdx.y;
    const int w = tid >> 6, l = tid & 63, lr = l & 15, lg = l >> 4;
    const int sm = tid >> 2, sk = tid & 3;
    const int kr = tid >> 3, c8 = (tid & 7) * 8;
    const int wkey = (kr >> 3) << 4;                   // write-side XOR key (row>>3)
    const int acol = ((w ^ lg) << 4) | lr;             // read col, pre-XORed with lg<<4

    const float* Gb = G + (size_t)gy * gslab;
    const unsigned short* pBh = Bh + (size_t)(gy * 64 + sm) * ldb + sk * 8;
    const unsigned short* pBl = Bl + (size_t)(gy * 64 + sm) * ldb + sk * 8;

    f32x4 acc[4] = {{0.f,0.f,0.f,0.f},{0.f,0.f,0.f,0.f},{0.f,0.f,0.f,0.f},{0.f,0.f,0.f,0.f}};

    for (int k0 = 0; k0 < K; k0 += 32) {
        float4 g0 = *(const float4*)&Gb[(size_t)(k0 + kr) * ldg + m0 + c8];
        float4 g1 = *(const float4*)&Gb[(size_t)(k0 + kr) * ldg + m0 + c8 + 4];
        uint4 vbh = *(const uint4*)pBh; uint4 vbl = *(const uint4*)pBl;
        pBh += 32; pBl += 32;
        __syncthreads();
        *(float4*)&At[kr * 64 + (c8 ^ wkey)] = g0;
        *(float4*)&At[kr * 64 + (c8 ^ wkey) + 4] = g1;
        *(uint4*)&BsH[sk][sm][0] = vbh;
        *(uint4*)&BsL[sk][sm][0] = vbl;
        __syncthreads();
        bf16x8 afh, afl;
#pragma unroll
        for (int j = 0; j < 8; ++j) {
            float v = At[(lg * 8 + j) * 64 + acol];
            afh[j] = (short)bfhi(v);
            afl[j] = (short)bfhi(bfres(v));
        }
#pragma unroll
        for (int nt = 0; nt < 4; ++nt) {
            bf16x8 bfh = *(const bf16x8*)&BsH[lg][nt * 16 + lr][0];
            bf16x8 bfl = *(const bf16x8*)&BsL[lg][nt * 16 + lr][0];
            acc[nt] = __builtin_amdgcn_mfma_f32_16x16x32_bf16(afh, bfh, acc[nt], 0, 0, 0);
            acc[nt] = __builtin_amdgcn_mfma_f32_16x16x32_bf16(afh, bfl, acc[nt], 0, 0, 0);
            acc[nt] = __builtin_amdgcn_mfma_f32_16x16x32_bf16(afl, bfh, acc[nt], 0, 0, 0);
        }
    }

    const int mrow0 = m0 + w * 16 + lg * 4;
    if (EPI == 0) {
#pragma unroll
        for (int nt = 0; nt < 4; ++nt) {
            int nn = gy * 64 + nt * 16 + lr;
            us4 h, lo;
#pragma unroll
            for (int j = 0; j < 4; ++j) {
                float v = acc[nt][j];
                h[j] = bfhi(v); lo[j] = bfhi(bfres(v));
            }
            *(us4*)&Oh[(size_t)nn * CCH + mrow0] = h;
            *(us4*)&Ol[(size_t)nn * CCH + mrow0] = lo;
        }
    } else {
        float bv[4];
#pragma unroll
        for (int j = 0; j < 4; ++j) bv[j] = bias[mrow0 + j];
#pragma unroll
        for (int nt = 0; nt < 4; ++nt) {
            int nn = gy * 64 + nt * 16 + lr;
            float lb = Lv[nn];
            size_t base = (size_t)(nn >> 6) * (CCH * NA) + (size_t)(nn & 63);
#pragma unroll
            for (int j = 0; j < 4; ++j)
                Ofp[base + (size_t)(mrow0 + j) * NA] = fmaf(bv[j], lb, acc[nt][j]);
        }
    }
}

extern "C" void kernel_launch(void* const* d_in, const int* in_sizes, int n_in,
                              void* d_out, int out_size, void* d_ws, size_t ws_size,
                              hipStream_t stream)
{
    (void)in_sizes; (void)n_in; (void)out_size; (void)ws_size;
    const float* queries  = (const float*)d_in[0];
    const float* features = (const float*)d_in[1];
    const float* Wq  = (const float*)d_in[2];
    const float* bq  = (const float*)d_in[3];
    const float* Wf  = (const float*)d_in[4];
    const float* bf  = (const float*)d_in[5];
    const float* Wf1 = (const float*)d_in[6];
    const float* bf1 = (const float*)d_in[7];
    float* out = (float*)d_out;
    char*  W   = (char*)d_ws;

    // ws layout (bytes), total ~16.4 MB (round-1-proven footprint):
    unsigned short* QTh = (unsigned short*)(W);                   // [1024][2048] 4MB
    unsigned short* QTl = (unsigned short*)(W + (4u << 20));      // 4MB
    unsigned short* FQh = (unsigned short*)(W + (8u << 20));      // [1024][2048] 4MB
    unsigned short* FQl = (unsigned short*)(W + (12u << 20));     // 4MB
    unsigned short* WqTh = (unsigned short*)(W + (16u << 20));            // [64][512] 64KB
    unsigned short* WqTl = (unsigned short*)(W + (16u << 20) + (64u << 10));
    float* bQ   = (float*)(W + (16u << 20) + (128u << 10));       // 4KB
    float* L    = (float*)(W + (16u << 20) + (128u << 10) + 4096);
    float* part = (float*)(W + (16u << 20) + (128u << 10) + 8192);// 64KB
    // stream-serialized region reuse:
    unsigned short* ATh = QTh;                                    // [1024][1024] 2MB (QT dead)
    unsigned short* ATl = (unsigned short*)(W + (2u << 20));      // 2MB
    unsigned short* TTh = FQh;                                    // [1024][2048] (FQ dead)
    unsigned short* TTl = FQl;

    float* attn = out;              // d_out[0 .. 1M)  fp32 [b][n][a]
    float* outm = out + 1048576;    // d_out[1M .. 3M) fp32 [b][c][a]

    // 1. WqT hi/lo (tiny)
    k_convWq<<<dim3(8), 256, 0, stream>>>(Wq, WqTh, WqTl);
    // 2. QT = (queries @ Wq + bq)^T, per-b scatter  (MFMA)
    k_gemm_A32<1><<<dim3(512, 1), 256, 0, stream>>>(queries, WqTh, WqTl, bq, QTh, QTl,
                                                    DQD, DQD);
    // 3. bQ = bf . Q
    k_bq<<<dim3(1024), 256, 0, stream>>>(QTh, QTl, bf, bQ);
    // 4. FQT = (Wf @ Q)^T  (MFMA)
    k_gemm_A32<0><<<dim3(32, 16), 256, 0, stream>>>(Wf, QTh, QTl, nullptr, FQh, FQl,
                                                    CCH, CCH);
    // 5. attn = softmax((feat @ FQ + bQ)/8)  + attnT hi/lo  (MFMA)
    k_scores<<<dim3(16, 16), 256, 0, stream>>>(features, FQh, FQl, bQ, attn, ATh, ATl);
    // 6. L = sum_n attn
    k_lsum1<<<dim3(16, 16), 256, 0, stream>>>(attn, part);
    k_lsum2<<<dim3(16), 64, 0, stream>>>(part, L);
    // 7. TT = (feat^T @ attn)^T per b  (MFMA, A via LDS transpose)
    k_gemm_T<0><<<dim3(32, 16), 256, 0, stream>>>(features, ATh, ATl, TTh, TTl,
                                                  nullptr, nullptr, nullptr,
                                                  HWD, CCH, HWD, (long)HWD * CCH);
    // 8. out = Wf1^T @ T + bf1 (x) L  (MFMA, A via LDS transpose)
    k_gemm_T<1><<<dim3(32, 16), 256, 0, stream>>>(Wf1, TTh, TTl, nullptr, nullptr,
                                                  outm, bf1, L,
                                                  CCH, CCH, CCH, 0L);
}

// Round 4
// 425.505 us; speedup vs baseline: 2.3162x; 1.1493x over previous
//
#include <hip/hip_runtime.h>
#include <math.h>

// SSCA restructured, all big contractions on MFMA via split-bf16 (hi+lo, 3-MFMA):
//   Q    = queries @ Wq + bq              -> QT hi/lo [ba][cp]      (MFMA, A-direct)
//   bQ   = bf . Q                         -> [ba]
//   FQ   = Wf @ Q                         -> FQT hi/lo [ba][ci]     (MFMA, A-direct)
//   attn = softmax((feat @ FQ + bQ)/8)    -> d_out fp32 + attnT hi/lo [ba][n] (MFMA, A-direct)
//   L    = sum_n attn                     -> [ba]
//   T    = feat^T @ attn (per b)          -> TT hi/lo [ba][ci]      (MFMA, LDS-transpose A)
//   out  = Wf1^T @ T + bf1 (x) L          -> d_out fp32 [b][c][a]   (MFMA, LDS-transpose A)
// All tile loops: register-prefetch + LDS double-buffer, ONE barrier per 32-K step.

#define CCH 2048
#define HWD 1024
#define BAD 1024
#define DQD 512
#define NA  64

typedef __attribute__((ext_vector_type(8))) short bf16x8;
typedef __attribute__((ext_vector_type(4))) float f32x4;
typedef __attribute__((ext_vector_type(4))) unsigned short us4;
typedef __attribute__((ext_vector_type(8))) unsigned short us8;

__device__ __forceinline__ unsigned short bfhi(float v) {
    return (unsigned short)(__float_as_uint(v) >> 16);
}
__device__ __forceinline__ float bfres(float v) {
    return v - __uint_as_float(__float_as_uint(v) & 0xffff0000u);
}
__device__ __forceinline__ float bf2f(unsigned short h) {
    return __uint_as_float(((unsigned)h) << 16);
}
__device__ __forceinline__ void cvt8(const float4& a0, const float4& a1,
                                     bf16x8& h, bf16x8& l) {
    float ar[8] = {a0.x, a0.y, a0.z, a0.w, a1.x, a1.y, a1.z, a1.w};
#pragma unroll
    for (int j = 0; j < 8; ++j) {
        h[j] = (short)bfhi(ar[j]);
        l[j] = (short)bfhi(bfres(ar[j]));
    }
}

// ---------- tiny: WqT hi/lo [a][dq] from Wq [dq][a] ----------
__global__ __launch_bounds__(256) void k_convWq(const float* __restrict__ Wq,
    unsigned short* __restrict__ hi, unsigned short* __restrict__ lo)
{
    __shared__ float t[64][65];
    const int tid = threadIdx.x;
    const int k0 = blockIdx.x * 64;
#pragma unroll
    for (int r = 0; r < 4; ++r) {
        int kr = (tid >> 4) + r * 16;
        int cc = (tid & 15) * 4;
        float4 v = *(const float4*)&Wq[(size_t)(k0 + kr) * NA + cc];
        t[kr][cc] = v.x; t[kr][cc + 1] = v.y; t[kr][cc + 2] = v.z; t[kr][cc + 3] = v.w;
    }
    __syncthreads();
#pragma unroll
    for (int r = 0; r < 2; ++r) {
        int a = (tid >> 3) + r * 32;
        int g = tid & 7;
        us8 h8, l8;
#pragma unroll
        for (int j = 0; j < 8; ++j) {
            float v = t[g * 8 + j][a];
            h8[j] = bfhi(v); l8[j] = bfhi(bfres(v));
        }
        *(us8*)&hi[(size_t)a * DQD + k0 + g * 8] = h8;
        *(us8*)&lo[(size_t)a * DQD + k0 + g * 8] = l8;
    }
}

// ---------- GEMM: A fp32 [M][K] k-contiguous DIRECT-to-reg, B bf16 hi/lo [N][K] via LDS dbuf ----
// 64x64 tile, 4 waves, split-3 MFMA, one barrier per 32-K step.
// EPI 0 (FQ):    Oh/Ol[(gy*64 + nloc)*CCH + m]
// EPI 1 (qproj): Oh/Ol[((m>>11)*64 + nloc)*CCH + (m&2047)], value += bias[nloc]
template <int EPI>
__global__ __launch_bounds__(256) void k_gemm_w(
    const float* __restrict__ A,
    const unsigned short* __restrict__ Bh, const unsigned short* __restrict__ Bl,
    const float* __restrict__ bias,
    unsigned short* __restrict__ Oh, unsigned short* __restrict__ Ol,
    int K, int ldb)
{
    __shared__ unsigned short BsH[2][4][64][8], BsL[2][4][64][8];
    const int tid = threadIdx.x;
    const int m0 = blockIdx.x * 64, gy = blockIdx.y;
    const int w = tid >> 6, l = tid & 63, lr = l & 15, lg = l >> 4;
    const int sm = tid >> 2, sk = tid & 3;

    const float* pA = A + (size_t)(m0 + w * 16 + lr) * K + lg * 8;
    const unsigned short* pBh = Bh + (size_t)(gy * 64 + sm) * ldb + sk * 8;
    const unsigned short* pBl = Bl + (size_t)(gy * 64 + sm) * ldb + sk * 8;

    f32x4 acc[4] = {{0.f,0.f,0.f,0.f},{0.f,0.f,0.f,0.f},{0.f,0.f,0.f,0.f},{0.f,0.f,0.f,0.f}};

    float4 a0 = *(const float4*)&pA[0];
    float4 a1 = *(const float4*)&pA[4];
    {
        uint4 vh = *(const uint4*)pBh, vl = *(const uint4*)pBl;
        pBh += 32; pBl += 32;
        *(uint4*)&BsH[0][sk][sm][0] = vh;
        *(uint4*)&BsL[0][sk][sm][0] = vl;
    }
    int buf = 0;
    for (int k0 = 0; k0 < K; k0 += 32) {
        const bool notlast = (k0 + 32 < K);
        float4 na0, na1; uint4 nh, nl;
        if (notlast) {
            na0 = *(const float4*)&pA[k0 + 32];
            na1 = *(const float4*)&pA[k0 + 36];
            nh = *(const uint4*)pBh; nl = *(const uint4*)pBl;
            pBh += 32; pBl += 32;
        }
        __syncthreads();
        bf16x8 afh, afl;
        cvt8(a0, a1, afh, afl);
#pragma unroll
        for (int nt = 0; nt < 4; ++nt) {
            bf16x8 bfh = *(const bf16x8*)&BsH[buf][lg][nt * 16 + lr][0];
            bf16x8 bfl = *(const bf16x8*)&BsL[buf][lg][nt * 16 + lr][0];
            acc[nt] = __builtin_amdgcn_mfma_f32_16x16x32_bf16(afh, bfh, acc[nt], 0, 0, 0);
            acc[nt] = __builtin_amdgcn_mfma_f32_16x16x32_bf16(afh, bfl, acc[nt], 0, 0, 0);
            acc[nt] = __builtin_amdgcn_mfma_f32_16x16x32_bf16(afl, bfh, acc[nt], 0, 0, 0);
        }
        if (notlast) {
            *(uint4*)&BsH[buf ^ 1][sk][sm][0] = nh;
            *(uint4*)&BsL[buf ^ 1][sk][sm][0] = nl;
            a0 = na0; a1 = na1;
        }
        buf ^= 1;
    }

    const int mrow0 = m0 + w * 16 + lg * 4;
    if (EPI == 0) {
#pragma unroll
        for (int nt = 0; nt < 4; ++nt) {
            int nn = gy * 64 + nt * 16 + lr;
            us4 h, lo;
#pragma unroll
            for (int j = 0; j < 4; ++j) {
                float v = acc[nt][j];
                h[j] = bfhi(v); lo[j] = bfhi(bfres(v));
            }
            *(us4*)&Oh[(size_t)nn * CCH + mrow0] = h;
            *(us4*)&Ol[(size_t)nn * CCH + mrow0] = lo;
        }
    } else {
        const int b = mrow0 >> 11, cp = mrow0 & 2047;
#pragma unroll
        for (int nt = 0; nt < 4; ++nt) {
            int nloc = nt * 16 + lr;
            float bb = bias[nloc];
            int row = b * 64 + nloc;
            us4 h, lo;
#pragma unroll
            for (int j = 0; j < 4; ++j) {
                float v = acc[nt][j] + bb;
                h[j] = bfhi(v); lo[j] = bfhi(bfres(v));
            }
            *(us4*)&Oh[(size_t)row * CCH + cp] = h;
            *(us4*)&Ol[(size_t)row * CCH + cp] = lo;
        }
    }
}

// ---------- bQ[ba] = sum_cp bf[cp] * Q[cp][ba] ----------
__global__ __launch_bounds__(256) void k_bq(const unsigned short* __restrict__ QTh,
    const unsigned short* __restrict__ QTl, const float* __restrict__ bf,
    float* __restrict__ bQ)
{
    const int row = blockIdx.x, tid = threadIdx.x;
    us8 h = *(const us8*)(QTh + (size_t)row * CCH + tid * 8);
    us8 l = *(const us8*)(QTl + (size_t)row * CCH + tid * 8);
    float s = 0.f;
#pragma unroll
    for (int j = 0; j < 8; ++j)
        s = fmaf(bf2f(h[j]) + bf2f(l[j]), bf[tid * 8 + j], s);
#pragma unroll
    for (int off = 1; off < 64; off <<= 1) s += __shfl_xor(s, off);
    __shared__ float ps[4];
    if ((tid & 63) == 0) ps[tid >> 6] = s;
    __syncthreads();
    if (tid == 0) bQ[row] = ps[0] + ps[1] + ps[2] + ps[3];
}

// ---------- scores + softmax: A=feat direct-reg, B=FQ LDS dbuf ----------
// grid (b=16, ntile=16) so same-b blocks land on one XCD (FQ L2 locality).
__global__ __launch_bounds__(256) void k_scores(
    const float* __restrict__ feat,
    const unsigned short* __restrict__ FQh, const unsigned short* __restrict__ FQl,
    const float* __restrict__ bQ, float* __restrict__ attn,
    unsigned short* __restrict__ ATh, unsigned short* __restrict__ ATl)
{
    __shared__ unsigned short BsH[2][4][64][8], BsL[2][4][64][8];
    const int tid = threadIdx.x;
    const int b = blockIdx.x, n0 = blockIdx.y * 64;
    const int w = tid >> 6, l = tid & 63, lr = l & 15, lg = l >> 4;
    const int sm = tid >> 2, sk = tid & 3;

    const float* pA = feat + ((size_t)b * HWD + n0 + w * 16 + lr) * CCH + lg * 8;
    const unsigned short* pBh = FQh + (size_t)(b * 64 + sm) * CCH + sk * 8;
    const unsigned short* pBl = FQl + (size_t)(b * 64 + sm) * CCH + sk * 8;

    f32x4 acc[4] = {{0.f,0.f,0.f,0.f},{0.f,0.f,0.f,0.f},{0.f,0.f,0.f,0.f},{0.f,0.f,0.f,0.f}};

    float4 a0 = *(const float4*)&pA[0];
    float4 a1 = *(const float4*)&pA[4];
    {
        uint4 vh = *(const uint4*)pBh, vl = *(const uint4*)pBl;
        pBh += 32; pBl += 32;
        *(uint4*)&BsH[0][sk][sm][0] = vh;
        *(uint4*)&BsL[0][sk][sm][0] = vl;
    }
    int buf = 0;
    for (int k0 = 0; k0 < CCH; k0 += 32) {
        const bool notlast = (k0 + 32 < CCH);
        float4 na0, na1; uint4 nh, nl;
        if (notlast) {
            na0 = *(const float4*)&pA[k0 + 32];
            na1 = *(const float4*)&pA[k0 + 36];
            nh = *(const uint4*)pBh; nl = *(const uint4*)pBl;
            pBh += 32; pBl += 32;
        }
        __syncthreads();
        bf16x8 afh, afl;
        cvt8(a0, a1, afh, afl);
#pragma unroll
        for (int nt = 0; nt < 4; ++nt) {
            bf16x8 bfh = *(const bf16x8*)&BsH[buf][lg][nt * 16 + lr][0];
            bf16x8 bfl = *(const bf16x8*)&BsL[buf][lg][nt * 16 + lr][0];
            acc[nt] = __builtin_amdgcn_mfma_f32_16x16x32_bf16(afh, bfh, acc[nt], 0, 0, 0);
            acc[nt] = __builtin_amdgcn_mfma_f32_16x16x32_bf16(afh, bfl, acc[nt], 0, 0, 0);
            acc[nt] = __builtin_amdgcn_mfma_f32_16x16x32_bf16(afl, bfh, acc[nt], 0, 0, 0);
        }
        if (notlast) {
            *(uint4*)&BsH[buf ^ 1][sk][sm][0] = nh;
            *(uint4*)&BsL[buf ^ 1][sk][sm][0] = nl;
            a0 = na0; a1 = na1;
        }
        buf ^= 1;
    }

    // softmax over 64 attrs; row n = n0 + w*16 + lg*4 + j, col a = nt*16 + lr.
    float bq4[4];
#pragma unroll
    for (int nt = 0; nt < 4; ++nt) bq4[nt] = bQ[b * NA + nt * 16 + lr];
    float pv[4][4];                                    // [j][nt]
#pragma unroll
    for (int j = 0; j < 4; ++j) {
        float v[4];
#pragma unroll
        for (int nt = 0; nt < 4; ++nt) v[nt] = (acc[nt][j] + bq4[nt]) * 0.125f;
        float m = fmaxf(fmaxf(v[0], v[1]), fmaxf(v[2], v[3]));
        m = fmaxf(m, __shfl_xor(m, 1));
        m = fmaxf(m, __shfl_xor(m, 2));
        m = fmaxf(m, __shfl_xor(m, 4));
        m = fmaxf(m, __shfl_xor(m, 8));
        float e[4], s = 0.f;
#pragma unroll
        for (int nt = 0; nt < 4; ++nt) { e[nt] = expf(v[nt] - m); s += e[nt]; }
        s += __shfl_xor(s, 1);
        s += __shfl_xor(s, 2);
        s += __shfl_xor(s, 4);
        s += __shfl_xor(s, 8);
        float inv = 1.f / s;
        const int nr = n0 + w * 16 + lg * 4 + j;
#pragma unroll
        for (int nt = 0; nt < 4; ++nt) {
            float av = e[nt] * inv;
            pv[j][nt] = av;
            attn[((size_t)b * HWD + nr) * NA + nt * 16 + lr] = av;
        }
    }
    // attnT hi/lo: per (nt) row a, 4 consecutive n values -> 8B stores
#pragma unroll
    for (int nt = 0; nt < 4; ++nt) {
        us4 h, lo;
#pragma unroll
        for (int j = 0; j < 4; ++j) {
            h[j] = bfhi(pv[j][nt]);
            lo[j] = bfhi(bfres(pv[j][nt]));
        }
        size_t ro = (size_t)(b * 64 + nt * 16 + lr) * HWD + n0 + w * 16 + lg * 4;
        *(us4*)&ATh[ro] = h;
        *(us4*)&ATl[ro] = lo;
    }
}

// ---------- L partials + final ----------
__global__ __launch_bounds__(256) void k_lsum1(const float* __restrict__ attn,
                                               float* __restrict__ part)
{
    const int g = blockIdx.x, b = blockIdx.y;
    const int a = threadIdx.x & 63, q = threadIdx.x >> 6;
    float s = 0.f;
#pragma unroll 4
    for (int n = g * 64 + q * 16; n < g * 64 + q * 16 + 16; ++n)
        s += attn[((size_t)b * HWD + n) * NA + a];
    __shared__ float p[4][64];
    p[q][a] = s;
    __syncthreads();
    if (q == 0) part[(size_t)g * BAD + b * NA + a] = p[0][a] + p[1][a] + p[2][a] + p[3][a];
}

__global__ __launch_bounds__(64) void k_lsum2(const float* __restrict__ part,
                                              float* __restrict__ L)
{
    int ba = blockIdx.x * 64 + threadIdx.x;
    float s = 0.f;
#pragma unroll
    for (int g = 0; g < 16; ++g) s += part[(size_t)g * BAD + ba];
    L[ba] = s;
}

// ---------- GEMM, A from k-major fp32 G[k][m] via XOR-swizzled LDS transpose (dbuf) ----------
// EPI 0 (tmat): grid (b=16, mtile=32); Oh/Ol[(gy*64 + nloc)*CCH + m]
// EPI 1 (out) : grid (mtile=32, ntile=16); Ofp[(nn>>6)*CCH*NA + m*NA + (nn&63)] += bias[m]*Lv[nn]
template <int EPI>
__global__ __launch_bounds__(256) void k_gemm_T(
    const float* __restrict__ G,
    const unsigned short* __restrict__ Bh, const unsigned short* __restrict__ Bl,
    unsigned short* __restrict__ Oh, unsigned short* __restrict__ Ol,
    float* __restrict__ Ofp, const float* __restrict__ bias, const float* __restrict__ Lv,
    int K, int ldg, int ldb, long gslab)
{
    __shared__ float At[2][2048];                      // [32 k][64 m] XOR-swizzled
    __shared__ unsigned short BsH[2][4][64][8], BsL[2][4][64][8];
    const int tid = threadIdx.x;
    const int m0 = (EPI == 0 ? blockIdx.y : blockIdx.x) * 64;
    const int gy = (EPI == 0 ? blockIdx.x : blockIdx.y);
    const int w = tid >> 6, l = tid & 63, lr = l & 15, lg = l >> 4;
    const int sm = tid >> 2, sk = tid & 3;
    const int kr = tid >> 3, c8 = (tid & 7) * 8;
    const int wkey = (kr >> 3) << 4;                   // write-side XOR key
    const int acol = ((w ^ lg) << 4) | lr;             // read col, pre-XORed

    const float* Gb = G + (size_t)gy * gslab + m0 + c8;
    const unsigned short* pBh = Bh + (size_t)(gy * 64 + sm) * ldb + sk * 8;
    const unsigned short* pBl = Bl + (size_t)(gy * 64 + sm) * ldb + sk * 8;

    f32x4 acc[4] = {{0.f,0.f,0.f,0.f},{0.f,0.f,0.f,0.f},{0.f,0.f,0.f,0.f},{0.f,0.f,0.f,0.f}};

    {
        float4 g0 = *(const float4*)&Gb[(size_t)kr * ldg];
        float4 g1 = *(const float4*)&Gb[(size_t)kr * ldg + 4];
        uint4 vh = *(const uint4*)pBh, vl = *(const uint4*)pBl;
        pBh += 32; pBl += 32;
        *(float4*)&At[0][kr * 64 + (c8 ^ wkey)] = g0;
        *(float4*)&At[0][kr * 64 + (c8 ^ wkey) + 4] = g1;
        *(uint4*)&BsH[0][sk][sm][0] = vh;
        *(uint4*)&BsL[0][sk][sm][0] = vl;
    }
    int buf = 0;
    for (int k0 = 0; k0 < K; k0 += 32) {
        const bool notlast = (k0 + 32 < K);
        float4 ng0, ng1; uint4 nh, nl;
        if (notlast) {
            ng0 = *(const float4*)&Gb[(size_t)(k0 + 32 + kr) * ldg];
            ng1 = *(const float4*)&Gb[(size_t)(k0 + 32 + kr) * ldg + 4];
            nh = *(const uint4*)pBh; nl = *(const uint4*)pBl;
            pBh += 32; pBl += 32;
        }
        __syncthreads();
        bf16x8 afh, afl;
#pragma unroll
        for (int j = 0; j < 8; ++j) {
            float v = At[buf][(lg * 8 + j) * 64 + acol];
            afh[j] = (short)bfhi(v);
            afl[j] = (short)bfhi(bfres(v));
        }
#pragma unroll
        for (int nt = 0; nt < 4; ++nt) {
            bf16x8 bfh = *(const bf16x8*)&BsH[buf][lg][nt * 16 + lr][0];
            bf16x8 bfl = *(const bf16x8*)&BsL[buf][lg][nt * 16 + lr][0];
            acc[nt] = __builtin_amdgcn_mfma_f32_16x16x32_bf16(afh, bfh, acc[nt], 0, 0, 0);
            acc[nt] = __builtin_amdgcn_mfma_f32_16x16x32_bf16(afh, bfl, acc[nt], 0, 0, 0);
            acc[nt] = __builtin_amdgcn_mfma_f32_16x16x32_bf16(afl, bfh, acc[nt], 0, 0, 0);
        }
        if (notlast) {
            *(float4*)&At[buf ^ 1][kr * 64 + (c8 ^ wkey)] = ng0;
            *(float4*)&At[buf ^ 1][kr * 64 + (c8 ^ wkey) + 4] = ng1;
            *(uint4*)&BsH[buf ^ 1][sk][sm][0] = nh;
            *(uint4*)&BsL[buf ^ 1][sk][sm][0] = nl;
        }
        buf ^= 1;
    }

    const int mrow0 = m0 + w * 16 + lg * 4;
    if (EPI == 0) {
#pragma unroll
        for (int nt = 0; nt < 4; ++nt) {
            int nn = gy * 64 + nt * 16 + lr;
            us4 h, lo;
#pragma unroll
            for (int j = 0; j < 4; ++j) {
                float v = acc[nt][j];
                h[j] = bfhi(v); lo[j] = bfhi(bfres(v));
            }
            *(us4*)&Oh[(size_t)nn * CCH + mrow0] = h;
            *(us4*)&Ol[(size_t)nn * CCH + mrow0] = lo;
        }
    } else {
        float bv[4];
#pragma unroll
        for (int j = 0; j < 4; ++j) bv[j] = bias[mrow0 + j];
#pragma unroll
        for (int nt = 0; nt < 4; ++nt) {
            int nn = gy * 64 + nt * 16 + lr;
            float lb = Lv[nn];
            size_t base = (size_t)(nn >> 6) * (CCH * NA) + (size_t)(nn & 63);
#pragma unroll
            for (int j = 0; j < 4; ++j)
                Ofp[base + (size_t)(mrow0 + j) * NA] = fmaf(bv[j], lb, acc[nt][j]);
        }
    }
}

extern "C" void kernel_launch(void* const* d_in, const int* in_sizes, int n_in,
                              void* d_out, int out_size, void* d_ws, size_t ws_size,
                              hipStream_t stream)
{
    (void)in_sizes; (void)n_in; (void)out_size; (void)ws_size;
    const float* queries  = (const float*)d_in[0];
    const float* features = (const float*)d_in[1];
    const float* Wq  = (const float*)d_in[2];
    const float* bq  = (const float*)d_in[3];
    const float* Wf  = (const float*)d_in[4];
    const float* bf  = (const float*)d_in[5];
    const float* Wf1 = (const float*)d_in[6];
    const float* bf1 = (const float*)d_in[7];
    float* out = (float*)d_out;
    char*  W   = (char*)d_ws;

    // ws layout (bytes), total ~16.4 MB (round-1/3-proven footprint):
    unsigned short* QTh = (unsigned short*)(W);                   // [1024][2048] 4MB
    unsigned short* QTl = (unsigned short*)(W + (4u << 20));      // 4MB
    unsigned short* FQh = (unsigned short*)(W + (8u << 20));      // [1024][2048] 4MB
    unsigned short* FQl = (unsigned short*)(W + (12u << 20));     // 4MB
    unsigned short* WqTh = (unsigned short*)(W + (16u << 20));            // [64][512] 64KB
    unsigned short* WqTl = (unsigned short*)(W + (16u << 20) + (64u << 10));
    float* bQ   = (float*)(W + (16u << 20) + (128u << 10));       // 4KB
    float* L    = (float*)(W + (16u << 20) + (128u << 10) + 4096);
    float* part = (float*)(W + (16u << 20) + (128u << 10) + 8192);// 64KB
    // stream-serialized region reuse:
    unsigned short* ATh = QTh;                                    // [1024][1024] 2MB (QT dead)
    unsigned short* ATl = (unsigned short*)(W + (2u << 20));      // 2MB
    unsigned short* TTh = FQh;                                    // [1024][2048] (FQ dead)
    unsigned short* TTl = FQl;

    float* attn = out;              // d_out[0 .. 1M)  fp32 [b][n][a]
    float* outm = out + 1048576;    // d_out[1M .. 3M) fp32 [b][c][a]

    // 1. WqT hi/lo (tiny)
    k_convWq<<<dim3(8), 256, 0, stream>>>(Wq, WqTh, WqTl);
    // 2. QT = (queries @ Wq + bq)^T, per-b scatter  (MFMA, A-direct)
    k_gemm_w<1><<<dim3(512, 1), 256, 0, stream>>>(queries, WqTh, WqTl, bq, QTh, QTl,
                                                  DQD, DQD);
    // 3. bQ = bf . Q
    k_bq<<<dim3(1024), 256, 0, stream>>>(QTh, QTl, bf, bQ);
    // 4. FQT = (Wf @ Q)^T  (MFMA, A-direct)
    k_gemm_w<0><<<dim3(32, 16), 256, 0, stream>>>(Wf, QTh, QTl, nullptr, FQh, FQl,
                                                  CCH, CCH);
    // 5. attn = softmax((feat @ FQ + bQ)/8)  + attnT hi/lo  (MFMA, A-direct)
    k_scores<<<dim3(16, 16), 256, 0, stream>>>(features, FQh, FQl, bQ, attn, ATh, ATl);
    // 6. L = sum_n attn
    k_lsum1<<<dim3(16, 16), 256, 0, stream>>>(attn, part);
    k_lsum2<<<dim3(16), 64, 0, stream>>>(part, L);
    // 7. TT = (feat^T @ attn)^T per b  (MFMA, LDS-transpose A, dbuf)
    k_gemm_T<0><<<dim3(16, 32), 256, 0, stream>>>(features, ATh, ATl, TTh, TTl,
                                                  nullptr, nullptr, nullptr,
                                                  HWD, CCH, HWD, (long)HWD * CCH);
    // 8. out = Wf1^T @ T + bf1 (x) L  (MFMA, LDS-transpose A, dbuf)
    k_gemm_T<1><<<dim3(32, 16), 256, 0, stream>>>(Wf1, TTh, TTl, nullptr, nullptr,
                                                  outm, bf1, L,
                                                  CCH, CCH, CCH, 0L);
}